// Round 7
// baseline (333.952 us; speedup 1.0000x reference)
//
#include <hip/hip_runtime.h>

#define N_NODES 100000
#define N_EDGES 1250000
#define D 64

#define BSHIFT 9
#define BUCKETS 196          // ceil(100000 / 512)
#define PAD_CAP 2400000      // padded srt capacity (E[total] ~1.81M, +300 sigma)
#define CNT_BLOCKS 640
#define CVT_BLOCKS 718
#define SC_BLOCKS 1280
#define NBLK 2048

typedef long long ll;
typedef unsigned int uint;

// round-to-nearest-even fp32 -> bf16
__device__ __forceinline__ ushort f2bf(float f) {
    uint u = __float_as_uint(f);
    u += 0x7fffu + ((u >> 16) & 1u);
    return (ushort)(u >> 16);
}

// ---------- prep: fill srt with N_NODES (pad sentinel), zero deg, zero rows ----------
__global__ __launch_bounds__(256) void prep_kernel(int* __restrict__ deg,
                                                   int* __restrict__ srt,
                                                   ushort* __restrict__ xb,
                                                   ushort* __restrict__ hidb) {
    const int i0 = blockIdx.x * 256 + threadIdx.x;
    const int stride = gridDim.x * 256;
    const int4 f4 = make_int4(N_NODES, N_NODES, N_NODES, N_NODES);
    for (int i = i0; i < (PAD_CAP + 64) / 4; i += stride) ((int4*)srt)[i] = f4;
    const int4 z4 = make_int4(0, 0, 0, 0);
    for (int i = i0; i < N_NODES / 4; i += stride) ((int4*)deg)[i] = z4;
    if (i0 < 16) {   // zero row (index N_NODES) in both bf16 operands: 128 B each
        uint2 z; z.x = 0; z.y = 0;
        ((uint2*)(xb   + (ll)N_NODES * D))[i0] = z;
        ((uint2*)(hidb + (ll)N_NODES * D))[i0] = z;
    }
}

// ---------- count degrees (global atomics, L2-resident) + fp32->bf16 cvt ----------
__global__ __launch_bounds__(512) void count_cvt_kernel(const int* __restrict__ dst,
                                                        int* __restrict__ deg,
                                                        const float* __restrict__ x,
                                                        ushort* __restrict__ xb) {
    const int tid = threadIdx.x;
    if (blockIdx.x >= CNT_BLOCKS) {
        const int n4 = N_NODES * D / 4;
        int i = (blockIdx.x - CNT_BLOCKS) * 512 + tid;
        for (; i < n4; i += CVT_BLOCKS * 512) {
            float4 v = ((const float4*)x)[i];
            ushort4 o;
            o.x = f2bf(v.x); o.y = f2bf(v.y); o.z = f2bf(v.z); o.w = f2bf(v.w);
            ((ushort4*)xb)[i] = o;
        }
        return;
    }
    int i = blockIdx.x * 512 + tid;
    for (; i < N_EDGES; i += CNT_BLOCKS * 512) atomicAdd(&deg[dst[i]], 1);
}

// ---------- scan 1: per-bucket totals of PADDED degrees ----------
__global__ __launch_bounds__(512) void degscan1_kernel(const int* __restrict__ deg,
                                                       int* __restrict__ bsum) {
    const int b = blockIdx.x, tid = threadIdx.x;
    const int lane = tid & 63, wv = tid >> 6;
    const int node0 = b << BSHIFT;
    const int nloc = min(512, N_NODES - node0);
    int pd = 0;
    if (tid < nloc) pd = (deg[node0 + tid] + 15) & ~15;
    int v = pd;
#pragma unroll
    for (int d = 1; d < 64; d <<= 1) v += __shfl_xor(v, d);
    __shared__ int ws[8];
    if (lane == 0) ws[wv] = v;
    __syncthreads();
    if (tid == 0) {
        int s = 0;
#pragma unroll
        for (int k = 0; k < 8; ++k) s += ws[k];
        bsum[b] = s;
    }
}

// ---------- scan 2: bucket-base scan + block scan of padded degs -> offs, cur ----------
__global__ __launch_bounds__(512) void degscan2_kernel(const int* __restrict__ deg,
                                                       const int* __restrict__ bsum,
                                                       int* __restrict__ offs,
                                                       int* __restrict__ cur) {
    __shared__ int sbase[256];
    __shared__ int wsum[8];
    __shared__ int tot;
    const int b = blockIdx.x, tid = threadIdx.x;
    const int lane = tid & 63, wv = tid >> 6;
    if (wv == 0) {   // exclusive scan over 196 bucket totals (4/lane + shfl)
        const int b4 = lane << 2;
        int c0 = (b4     < BUCKETS) ? bsum[b4]     : 0;
        int c1 = (b4 + 1 < BUCKETS) ? bsum[b4 + 1] : 0;
        int c2 = (b4 + 2 < BUCKETS) ? bsum[b4 + 2] : 0;
        int c3 = (b4 + 3 < BUCKETS) ? bsum[b4 + 3] : 0;
        const int s1 = c0 + c1, sum = s1 + c2 + c3;
        int run = sum;
#pragma unroll
        for (int d = 1; d < 64; d <<= 1) {
            int t = __shfl_up(run, d);
            if (lane >= d) run += t;
        }
        const int lex = run - sum;
        sbase[b4]     = lex;
        sbase[b4 + 1] = lex + c0;
        sbase[b4 + 2] = lex + s1;
        sbase[b4 + 3] = lex + s1 + c2;
        if (lane == 63) tot = run;   // grand total of padded lengths
    }
    __syncthreads();
    const int gbase = sbase[b];
    const int node0 = b << BSHIFT;
    const int nloc = min(512, N_NODES - node0);
    int pd = (tid < nloc) ? ((deg[node0 + tid] + 15) & ~15) : 0;
    int v = pd;
#pragma unroll
    for (int d = 1; d < 64; d <<= 1) {
        int t = __shfl_up(v, d);
        if (lane >= d) v += t;
    }
    if (lane == 63) wsum[wv] = v;
    __syncthreads();
    int woff = 0;
#pragma unroll
    for (int k = 0; k < 8; ++k) woff += (k < wv) ? wsum[k] : 0;
    const int excl = v + woff - pd;
    if (tid < nloc) {
        offs[node0 + tid] = gbase + excl;   // coalesced
        cur[node0 + tid]  = gbase + excl;
    }
    if (b == BUCKETS - 1 && tid == 0) offs[N_NODES] = tot;   // padded sentinel
}

// ---------- scatter: srt[p] = src, p = atomicAdd(cur[dst]) ----------
// Pads (slots deg..pdeg of each segment) keep the prep-filled N_NODES sentinel.
__global__ __launch_bounds__(256) void scatter_kernel(const int* __restrict__ src,
                                                      const int* __restrict__ dst,
                                                      int* __restrict__ cur,
                                                      int* __restrict__ srt) {
    int i = blockIdx.x * 256 + threadIdx.x;
    for (; i < N_EDGES; i += SC_BLOCKS * 256) {
        int d = dst[i], s = src[i];
        int p = atomicAdd(&cur[d], 1);
        srt[p] = s;
    }
}

// ---------- fused pull + linear: padded bf16 gather, node-pair, 8 in flight ----------
// Padded CSR removes all clamps/masks (pad slots gather the zero row at index
// N_NODES). Per node per iteration: ONE coalesced srt load (lanes 0-15 hold the
// 16 edge indices) + 4 shfl-distributes + 4 uint2 gathers. 10 VMEM/iter (was 16)
// and ~50-reg live set targeting the 64-VGPR occupancy cliff from BELOW.
// NO min-waves launch bound (R4: forcing -> spills).
#define UACC(V, AX, AY, AZ, AW)                               \
    AX += __uint_as_float((V).x << 16);                       \
    AY += __uint_as_float((V).x & 0xffff0000u);               \
    AZ += __uint_as_float((V).y << 16);                       \
    AW += __uint_as_float((V).y & 0xffff0000u);

template<int EMIT>
__global__ __launch_bounds__(256) void fused_layer(const ushort* __restrict__ hb,
                                                   const int* __restrict__ offs,
                                                   const int* __restrict__ srt,
                                                   const float* __restrict__ W1,
                                                   const float* __restrict__ b1,
                                                   float* __restrict__ out,
                                                   ushort* __restrict__ outb) {
    __shared__ __align__(16) float rbA[4][64];
    __shared__ __align__(16) float rbB[4][64];
    const int tid  = threadIdx.x;
    const int lane = tid & 63;
    const int wid  = tid >> 6;
    const int g    = lane >> 4;          // gather group 0..3
    const int sub  = lane & 15;          // uint2 (4 bf16) within the row; also srt slot
    const uint roff = (uint)sub << 3;    // byte offset within 128-B row
    const int goff = g << 2;
    const int gw   = blockIdx.x * 4 + wid;
    const int GW   = NBLK * 4;
    const char* hbase = (const char*)hb;

    const float4* wrow = (const float4*)(W1 + lane * D);
    const float bj = b1[lane];

    for (int p = gw; p < (N_NODES >> 1); p += GW) {
        const int nA = p << 1;
        const int2 o2 = *(const int2*)(offs + nA);   // begA, endA(=begB)
        const int begA = o2.x;
        const int endA = o2.y;
        const int endB = offs[nA + 2];               // offs[N] sentinel

        float aAx = 0.f, aAy = 0.f, aAz = 0.f, aAw = 0.f;
        float aBx = 0.f, aBy = 0.f, aBz = 0.f, aBw = 0.f;

        int ebA = begA, ebB = endA;
        while (ebA < endA || ebB < endB) {
            // one coalesced 64-B srt load per node; exhausted side -> zero row
            int siA = (ebA < endA) ? srt[ebA + sub] : N_NODES;
            int siB = (ebB < endB) ? srt[ebB + sub] : N_NODES;
            const int iA0 = __shfl(siA, goff);
            const int iA1 = __shfl(siA, goff + 1);
            const int iA2 = __shfl(siA, goff + 2);
            const int iA3 = __shfl(siA, goff + 3);
            const int iB0 = __shfl(siB, goff);
            const int iB1 = __shfl(siB, goff + 1);
            const int iB2 = __shfl(siB, goff + 2);
            const int iB3 = __shfl(siB, goff + 3);
            const uint2 vA0 = *(const uint2*)(hbase + (((uint)iA0 << 7) + roff));
            const uint2 vA1 = *(const uint2*)(hbase + (((uint)iA1 << 7) + roff));
            const uint2 vA2 = *(const uint2*)(hbase + (((uint)iA2 << 7) + roff));
            const uint2 vA3 = *(const uint2*)(hbase + (((uint)iA3 << 7) + roff));
            const uint2 vB0 = *(const uint2*)(hbase + (((uint)iB0 << 7) + roff));
            const uint2 vB1 = *(const uint2*)(hbase + (((uint)iB1 << 7) + roff));
            const uint2 vB2 = *(const uint2*)(hbase + (((uint)iB2 << 7) + roff));
            const uint2 vB3 = *(const uint2*)(hbase + (((uint)iB3 << 7) + roff));
            UACC(vA0, aAx, aAy, aAz, aAw);
            UACC(vA1, aAx, aAy, aAz, aAw);
            UACC(vA2, aAx, aAy, aAz, aAw);
            UACC(vA3, aAx, aAy, aAz, aAw);
            UACC(vB0, aBx, aBy, aBz, aBw);
            UACC(vB1, aBx, aBy, aBz, aBw);
            UACC(vB2, aBx, aBy, aBz, aBw);
            UACC(vB3, aBx, aBy, aBz, aBw);
            ebA += 16; ebB += 16;
        }

        // cross-group reduce: after xor16+xor32 every lane holds the full sum
        aAx += __shfl_xor(aAx, 16); aAy += __shfl_xor(aAy, 16);
        aAz += __shfl_xor(aAz, 16); aAw += __shfl_xor(aAw, 16);
        aBx += __shfl_xor(aBx, 16); aBy += __shfl_xor(aBy, 16);
        aBz += __shfl_xor(aBz, 16); aBw += __shfl_xor(aBw, 16);
        aAx += __shfl_xor(aAx, 32); aAy += __shfl_xor(aAy, 32);
        aAz += __shfl_xor(aAz, 32); aAw += __shfl_xor(aAw, 32);
        aBx += __shfl_xor(aBx, 32); aBy += __shfl_xor(aBy, 32);
        aBz += __shfl_xor(aBz, 32); aBw += __shfl_xor(aBw, 32);

        if (g == 0) {
            float4 t; t.x = aAx; t.y = aAy; t.z = aAz; t.w = aAw;
            *((float4*)rbA[wid] + sub) = t;     // lanes 0-15 consecutive: conflict-free
        }
        if (g == 1) {
            float4 t; t.x = aBx; t.y = aBy; t.z = aBz; t.w = aBw;
            *((float4*)rbB[wid] + sub) = t;
        }
        // wave-internal LDS RAW: compiler inserts lgkmcnt wait; no barrier needed

        float oA = bj, oB = bj;
        const float4* ra = (const float4*)rbA[wid];
        const float4* rb = (const float4*)rbB[wid];
#pragma unroll
        for (int k4 = 0; k4 < 16; ++k4) {
            const float4 w  = wrow[k4];          // L1-resident (16KB), per-lane row
            const float4 rA = ra[k4];            // LDS broadcast, conflict-free
            const float4 rB = rb[k4];
            oA += rA.x * w.x + rA.y * w.y + rA.z * w.z + rA.w * w.w;
            oB += rB.x * w.x + rB.y * w.y + rB.z * w.z + rB.w * w.w;
        }
        __builtin_nontemporal_store(oA, out + (ll)nA * D + lane);
        __builtin_nontemporal_store(oB, out + (ll)(nA + 1) * D + lane);
        if (EMIT) {
            outb[(ll)nA * D + lane]       = f2bf(oA);   // plain store: keep L2-hot
            outb[(ll)(nA + 1) * D + lane] = f2bf(oB);
        }
    }
}

extern "C" void kernel_launch(void* const* d_in, const int* in_sizes, int n_in,
                              void* d_out, int out_size, void* d_ws, size_t ws_size,
                              hipStream_t stream) {
    const float* x  = (const float*)d_in[0];   // [N, D]
    const int* edge = (const int*)d_in[1];     // [2, E]: src row then dst row
    const float* W1 = (const float*)d_in[2];   // [D, D]
    const float* b1 = (const float*)d_in[3];   // [D]

    const int* src = edge;
    const int* dst = edge + N_EDGES;

    float* out = (float*)d_out;                    // output 0: [N, D]
    float* hid = (float*)d_out + (ll)N_NODES * D;  // output 1: [N, D]

    // xb (bf16 copy of x, N+1 rows incl zero row) lives in the `out` region:
    // only read during layer 1 (which writes hid); layer 2 overwrites out fully.
    ushort* xb = (ushort*)d_out;                   // (N+1)*128 B = 12.8 MB < 25.6 MB

    // workspace layout (~23.7 MiB; 25.6 MB proven available)
    char* ws = (char*)d_ws;
    int* deg    = (int*)ws;  ws += ((size_t)N_NODES * 4 + 255) & ~255ull;        // [N]
    int* cur    = (int*)ws;  ws += ((size_t)N_NODES * 4 + 255) & ~255ull;        // [N]
    int* offs   = (int*)ws;  ws += ((size_t)(N_NODES + 1) * 4 + 255) & ~255ull;  // [N+1]
    int* bsum   = (int*)ws;  ws += 1024;                                         // [196]
    int* srt    = (int*)ws;  ws += ((size_t)(PAD_CAP + 64) * 4 + 255) & ~255ull; // padded
    ushort* hidb = (ushort*)ws;                    // [(N+1), D] bf16 incl zero row

    // ---- build padded CSR: count -> scan -> scatter ----
    prep_kernel<<<1024, 256, 0, stream>>>(deg, srt, xb, hidb);
    count_cvt_kernel<<<CNT_BLOCKS + CVT_BLOCKS, 512, 0, stream>>>(dst, deg, x, xb);
    degscan1_kernel<<<BUCKETS, 512, 0, stream>>>(deg, bsum);
    degscan2_kernel<<<BUCKETS, 512, 0, stream>>>(deg, bsum, offs, cur);
    scatter_kernel<<<SC_BLOCKS, 256, 0, stream>>>(src, dst, cur, srt);

    // ---- layer 1: hid = segsum(x) @ W1^T + b1 (bf16 gather; emits bf16 hid) ----
    fused_layer<1><<<NBLK, 256, 0, stream>>>(xb, offs, srt, W1, b1, hid, hidb);
    // ---- layer 2: out = segsum(hid) @ W1^T + b1 (bf16 gather) ----
    fused_layer<0><<<NBLK, 256, 0, stream>>>(hidb, offs, srt, W1, b1, out, (ushort*)nullptr);
}

// Round 8
// 272.696 us; speedup vs baseline: 1.2246x; 1.2246x over previous
//
#include <hip/hip_runtime.h>

#define N_NODES 100000
#define N_EDGES 1250000
#define D 64

#define BSHIFT 9
#define BUCKETS 196          // ceil(100000 / 512)
#define CAP 8192             // tmp capacity per bucket (mean 6378, +22 sigma)
#define CHUNK 4096           // edges per bucketA block
#define PA_BLOCKS ((N_EDGES + CHUNK - 1) / CHUNK)   // 306
#define LCAP 64              // LDS list capacity per bucket per chunk (mean 21, max<64)
#define CNT_BLOCKS 640
#define CVT_BLOCKS 718
#define PAD_SRT 2750128      // worst-case padded length: E + 15*N, +slack
#define NBLK 2048

typedef long long ll;
typedef unsigned int uint;

// round-to-nearest-even fp32 -> bf16
__device__ __forceinline__ ushort f2bf(float f) {
    uint u = __float_as_uint(f);
    u += 0x7fffu + ((u >> 16) & 1u);
    return (ushort)(u >> 16);
}

// ---------- init: zero deg; cursor[b]=b*CAP; zero rows (index N_NODES) ----------
__global__ __launch_bounds__(256) void init_kernel(int* __restrict__ deg,
                                                   int* __restrict__ cursor,
                                                   ushort* __restrict__ xb,
                                                   ushort* __restrict__ hidb) {
    const int i0 = blockIdx.x * 256 + threadIdx.x;
    const int stride = gridDim.x * 256;
    const int4 z4 = make_int4(0, 0, 0, 0);
    for (int i = i0; i < N_NODES / 4; i += stride) ((int4*)deg)[i] = z4;
    if (i0 < BUCKETS) cursor[i0] = i0 * CAP;
    if (i0 < 16) {   // zero row (index N_NODES) in both bf16 operands: 128 B each
        uint2 z; z.x = 0; z.y = 0;
        ((uint2*)(xb   + (ll)N_NODES * D))[i0] = z;
        ((uint2*)(hidb + (ll)N_NODES * D))[i0] = z;
    }
}

// ---------- count degrees (global atomics, L2-resident) + fp32->bf16 cvt ----------
// No LDS: full occupancy for both roles (R6's merged grid forced 49KB on cvt).
__global__ __launch_bounds__(512) void count_cvt_kernel(const int* __restrict__ dst,
                                                        int* __restrict__ deg,
                                                        const float* __restrict__ x,
                                                        ushort* __restrict__ xb) {
    const int tid = threadIdx.x;
    if (blockIdx.x >= CNT_BLOCKS) {
        const int n4 = N_NODES * D / 4;
        int i = (blockIdx.x - CNT_BLOCKS) * 512 + tid;
        for (; i < n4; i += CVT_BLOCKS * 512) {
            float4 v = ((const float4*)x)[i];
            ushort4 o;
            o.x = f2bf(v.x); o.y = f2bf(v.y); o.z = f2bf(v.z); o.w = f2bf(v.w);
            ((ushort4*)xb)[i] = o;
        }
        return;
    }
    int i = blockIdx.x * 512 + tid;
    for (; i < N_EDGES; i += CNT_BLOCKS * 512) atomicAdd(&deg[dst[i]], 1);
}

// ---------- pass A: bin edges into 196 coarse buckets (LDS lists, coalesced flush) ----------
__global__ __launch_bounds__(512) void bucketA_kernel(const int* __restrict__ src,
                                                      const int* __restrict__ dst,
                                                      int* __restrict__ cursor,
                                                      int* __restrict__ tmp) {
    __shared__ int lcnt[BUCKETS];
    __shared__ int gbs[BUCKETS];
    __shared__ int list[BUCKETS * LCAP];   // ~49 KB
    int tid = threadIdx.x;
    if (tid < BUCKETS) lcnt[tid] = 0;
    __syncthreads();

    int base = blockIdx.x * CHUNK;
    int nE = min(CHUNK, N_EDGES - base);
    for (int i = tid; i < nE; i += 512) {
        int e = base + i;
        int s = src[e], d = dst[e];
        int b = d >> BSHIFT;
        int p = atomicAdd(&lcnt[b], 1);            // LDS atomic, cheap
        list[b * LCAP + p] = s | ((d & 511) << 17); // src:17b, dstLow:9b
    }
    __syncthreads();

    if (tid < BUCKETS) gbs[tid] = atomicAdd(&cursor[tid], lcnt[tid]);  // parallel
    __syncthreads();

    int wv = tid >> 6, lane = tid & 63;
    for (int b = wv; b < BUCKETS; b += 8) {        // 8 waves, fire-and-forget stores
        int c = lcnt[b];
        if (lane < c) tmp[gbs[b] + lane] = list[b * LCAP + lane];
    }
}

// ---------- scan 1: per-bucket totals of PADDED degrees ----------
__global__ __launch_bounds__(512) void degscan1_kernel(const int* __restrict__ deg,
                                                       int* __restrict__ bsum) {
    const int b = blockIdx.x, tid = threadIdx.x;
    const int lane = tid & 63, wv = tid >> 6;
    const int node0 = b << BSHIFT;
    const int nloc = min(512, N_NODES - node0);
    int pd = 0;
    if (tid < nloc) pd = (deg[node0 + tid] + 15) & ~15;
    int v = pd;
#pragma unroll
    for (int d = 1; d < 64; d <<= 1) v += __shfl_xor(v, d);
    __shared__ int wsm[8];
    if (lane == 0) wsm[wv] = v;
    __syncthreads();
    if (tid == 0) {
        int s = 0;
#pragma unroll
        for (int k = 0; k < 8; ++k) s += wsm[k];
        bsum[b] = s;
    }
}

// ---------- scan 2: bucket-base scan + block scan of padded degs -> offs ----------
__global__ __launch_bounds__(512) void degscan2_kernel(const int* __restrict__ deg,
                                                       const int* __restrict__ bsum,
                                                       int* __restrict__ offs) {
    __shared__ int sbase[256];
    __shared__ int wsum[8];
    __shared__ int tot;
    const int b = blockIdx.x, tid = threadIdx.x;
    const int lane = tid & 63, wv = tid >> 6;
    if (wv == 0) {   // exclusive scan over 196 bucket totals (4/lane + shfl)
        const int b4 = lane << 2;
        int c0 = (b4     < BUCKETS) ? bsum[b4]     : 0;
        int c1 = (b4 + 1 < BUCKETS) ? bsum[b4 + 1] : 0;
        int c2 = (b4 + 2 < BUCKETS) ? bsum[b4 + 2] : 0;
        int c3 = (b4 + 3 < BUCKETS) ? bsum[b4 + 3] : 0;
        const int s1 = c0 + c1, sum = s1 + c2 + c3;
        int run = sum;
#pragma unroll
        for (int d = 1; d < 64; d <<= 1) {
            int t = __shfl_up(run, d);
            if (lane >= d) run += t;
        }
        const int lex = run - sum;
        sbase[b4]     = lex;
        sbase[b4 + 1] = lex + c0;
        sbase[b4 + 2] = lex + s1;
        sbase[b4 + 3] = lex + s1 + c2;
        if (lane == 63) tot = run;   // grand total of padded lengths
    }
    __syncthreads();
    const int gbase = sbase[b];
    const int node0 = b << BSHIFT;
    const int nloc = min(512, N_NODES - node0);
    int pd = (tid < nloc) ? ((deg[node0 + tid] + 15) & ~15) : 0;
    int v = pd;
#pragma unroll
    for (int d = 1; d < 64; d <<= 1) {
        int t = __shfl_up(v, d);
        if (lane >= d) v += t;
    }
    if (lane == 63) wsum[wv] = v;
    __syncthreads();
    int woff = 0;
#pragma unroll
    for (int k = 0; k < 8; ++k) woff += (k < wv) ? wsum[k] : 0;
    const int excl = v + woff - pd;
    if (tid < nloc) offs[node0 + tid] = gbase + excl;   // coalesced
    if (b == BUCKETS - 1 && tid == 0) offs[N_NODES] = tot;
}

// ---------- pass B: scatter tmp -> padded srt via LDS cursors; fill pads ----------
// Lean: no hist, no in-block scan (offs already global). Scatter hits the
// bucket's ~30KB srt window (L2-buffered). Pad slots (<=15/node) filled here —
// no global prefill of srt needed.
__global__ __launch_bounds__(512) void bucketB_kernel(const int* __restrict__ cursor,
                                                      const int* __restrict__ tmp,
                                                      const int* __restrict__ offs,
                                                      int* __restrict__ srt) {
    __shared__ int cur[512];
    const int b = blockIdx.x, tid = threadIdx.x;
    const int cbase = b * CAP;
    const int cnt = cursor[b] - cbase;
    const int node0 = b << BSHIFT;
    const int nloc = min(512, N_NODES - node0);
    if (tid < nloc) cur[tid] = offs[node0 + tid];
    __syncthreads();

    for (int i = tid; i < cnt; i += 512) {
        int v = tmp[cbase + i];            // L2-hot (second read)
        int ln = v >> 17;
        int p = atomicAdd(&cur[ln], 1);
        srt[p] = v & 0x1FFFF;
    }
    __syncthreads();

    if (tid < nloc) {                      // fill pads with sentinel (zero row)
        const int e = offs[node0 + tid + 1];   // contiguous layout; offs[N] sentinel
        for (int q = cur[tid]; q < e; ++q) srt[q] = N_NODES;
    }
}

// ---------- fused pull + linear: padded bf16 gather, node-pair, 8 in flight ----------
// Padded CSR: no clamps/masks (pad slots gather the zero row at index N_NODES).
// Per node per iteration: ONE coalesced srt load (lanes hold the 16 slot
// indices) + shfl distribute + 4 uint2 gathers -> 10 VMEM/iter, ~55-reg live
// set targeting the 64-VGPR occupancy cliff from BELOW.
// NO min-waves launch bound (R4: forcing -> spills).
#define UACC(V, AX, AY, AZ, AW)                               \
    AX += __uint_as_float((V).x << 16);                       \
    AY += __uint_as_float((V).x & 0xffff0000u);               \
    AZ += __uint_as_float((V).y << 16);                       \
    AW += __uint_as_float((V).y & 0xffff0000u);

template<int EMIT>
__global__ __launch_bounds__(256) void fused_layer(const ushort* __restrict__ hb,
                                                   const int* __restrict__ offs,
                                                   const int* __restrict__ srt,
                                                   const float* __restrict__ W1,
                                                   const float* __restrict__ b1,
                                                   float* __restrict__ out,
                                                   ushort* __restrict__ outb) {
    __shared__ __align__(16) float rbA[4][64];
    __shared__ __align__(16) float rbB[4][64];
    const int tid  = threadIdx.x;
    const int lane = tid & 63;
    const int wid  = tid >> 6;
    const int g    = lane >> 4;          // gather group 0..3
    const int sub  = lane & 15;          // uint2 (4 bf16) within row; also srt slot
    const uint roff = (uint)sub << 3;    // byte offset within 128-B row
    const int goff = g << 2;
    const int gw   = blockIdx.x * 4 + wid;
    const int GW   = NBLK * 4;
    const char* hbase = (const char*)hb;

    const float4* wrow = (const float4*)(W1 + lane * D);
    const float bj = b1[lane];

    for (int p = gw; p < (N_NODES >> 1); p += GW) {
        const int nA = p << 1;
        const int2 o2 = *(const int2*)(offs + nA);   // begA, endA(=begB)
        const int begA = o2.x;
        const int endA = o2.y;
        const int endB = offs[nA + 2];               // offs[N] sentinel

        float aAx = 0.f, aAy = 0.f, aAz = 0.f, aAw = 0.f;
        float aBx = 0.f, aBy = 0.f, aBz = 0.f, aBw = 0.f;

        int ebA = begA, ebB = endA;
        while (ebA < endA || ebB < endB) {
            // one coalesced 64-B srt load per node; exhausted side -> clamped
            // in-segment address (L1-hot) overridden with the zero-row sentinel
            const int adA = (ebA < endA) ? ebA : begA;
            const int adB = (ebB < endB) ? ebB : endA;
            int siA = srt[adA + sub];
            int siB = srt[adB + sub];
            siA = (ebA < endA) ? siA : N_NODES;
            siB = (ebB < endB) ? siB : N_NODES;
            const int iA0 = __shfl(siA, goff);
            const int iA1 = __shfl(siA, goff + 1);
            const int iA2 = __shfl(siA, goff + 2);
            const int iA3 = __shfl(siA, goff + 3);
            const int iB0 = __shfl(siB, goff);
            const int iB1 = __shfl(siB, goff + 1);
            const int iB2 = __shfl(siB, goff + 2);
            const int iB3 = __shfl(siB, goff + 3);
            const uint2 vA0 = *(const uint2*)(hbase + (((uint)iA0 << 7) + roff));
            const uint2 vA1 = *(const uint2*)(hbase + (((uint)iA1 << 7) + roff));
            const uint2 vA2 = *(const uint2*)(hbase + (((uint)iA2 << 7) + roff));
            const uint2 vA3 = *(const uint2*)(hbase + (((uint)iA3 << 7) + roff));
            const uint2 vB0 = *(const uint2*)(hbase + (((uint)iB0 << 7) + roff));
            const uint2 vB1 = *(const uint2*)(hbase + (((uint)iB1 << 7) + roff));
            const uint2 vB2 = *(const uint2*)(hbase + (((uint)iB2 << 7) + roff));
            const uint2 vB3 = *(const uint2*)(hbase + (((uint)iB3 << 7) + roff));
            UACC(vA0, aAx, aAy, aAz, aAw);
            UACC(vA1, aAx, aAy, aAz, aAw);
            UACC(vA2, aAx, aAy, aAz, aAw);
            UACC(vA3, aAx, aAy, aAz, aAw);
            UACC(vB0, aBx, aBy, aBz, aBw);
            UACC(vB1, aBx, aBy, aBz, aBw);
            UACC(vB2, aBx, aBy, aBz, aBw);
            UACC(vB3, aBx, aBy, aBz, aBw);
            ebA += 16; ebB += 16;
        }

        // cross-group reduce: after xor16+xor32 every lane holds the full sum
        aAx += __shfl_xor(aAx, 16); aAy += __shfl_xor(aAy, 16);
        aAz += __shfl_xor(aAz, 16); aAw += __shfl_xor(aAw, 16);
        aBx += __shfl_xor(aBx, 16); aBy += __shfl_xor(aBy, 16);
        aBz += __shfl_xor(aBz, 16); aBw += __shfl_xor(aBw, 16);
        aAx += __shfl_xor(aAx, 32); aAy += __shfl_xor(aAy, 32);
        aAz += __shfl_xor(aAz, 32); aAw += __shfl_xor(aAw, 32);
        aBx += __shfl_xor(aBx, 32); aBy += __shfl_xor(aBy, 32);
        aBz += __shfl_xor(aBz, 32); aBw += __shfl_xor(aBw, 32);

        if (g == 0) {
            float4 t; t.x = aAx; t.y = aAy; t.z = aAz; t.w = aAw;
            *((float4*)rbA[wid] + sub) = t;     // lanes 0-15 consecutive: conflict-free
        }
        if (g == 1) {
            float4 t; t.x = aBx; t.y = aBy; t.z = aBz; t.w = aBw;
            *((float4*)rbB[wid] + sub) = t;
        }
        // wave-internal LDS RAW: compiler inserts lgkmcnt wait; no barrier needed

        float oA = bj, oB = bj;
        const float4* ra = (const float4*)rbA[wid];
        const float4* rb = (const float4*)rbB[wid];
#pragma unroll
        for (int k4 = 0; k4 < 16; ++k4) {
            const float4 w  = wrow[k4];          // L1-resident (16KB), per-lane row
            const float4 rA = ra[k4];            // LDS broadcast, conflict-free
            const float4 rB = rb[k4];
            oA += rA.x * w.x + rA.y * w.y + rA.z * w.z + rA.w * w.w;
            oB += rB.x * w.x + rB.y * w.y + rB.z * w.z + rB.w * w.w;
        }
        __builtin_nontemporal_store(oA, out + (ll)nA * D + lane);
        __builtin_nontemporal_store(oB, out + (ll)(nA + 1) * D + lane);
        if (EMIT) {
            outb[(ll)nA * D + lane]       = f2bf(oA);   // plain store: keep L2-hot
            outb[(ll)(nA + 1) * D + lane] = f2bf(oB);
        }
    }
}

extern "C" void kernel_launch(void* const* d_in, const int* in_sizes, int n_in,
                              void* d_out, int out_size, void* d_ws, size_t ws_size,
                              hipStream_t stream) {
    const float* x  = (const float*)d_in[0];   // [N, D]
    const int* edge = (const int*)d_in[1];     // [2, E]: src row then dst row
    const float* W1 = (const float*)d_in[2];   // [D, D]
    const float* b1 = (const float*)d_in[3];   // [D]

    const int* src = edge;
    const int* dst = edge + N_EDGES;

    float* out = (float*)d_out;                    // output 0: [N, D]
    float* hid = (float*)d_out + (ll)N_NODES * D;  // output 1: [N, D]

    // xb (bf16 copy of x, N+1 rows incl zero row) lives in the `out` region:
    // only read during layer 1 (which writes hid); layer 2 overwrites out fully.
    ushort* xb = (ushort*)d_out;                   // 12.8 MB < 25.6 MB

    // workspace layout (~24.6 MiB; 25.6 MB proven available)
    char* ws = (char*)d_ws;
    int* deg    = (int*)ws;  ws += ((size_t)N_NODES * 4 + 255) & ~255ull;        // [N]
    int* offs   = (int*)ws;  ws += ((size_t)(N_NODES + 1) * 4 + 255) & ~255ull;  // [N+1]
    int* bsum   = (int*)ws;  ws += 1024;                                         // [196]
    int* cursor = (int*)ws;  ws += 1024;                                         // [196]
    int* srt    = (int*)ws;  ws += (size_t)PAD_SRT * 4;                          // 11.0 MB
    // hidb [(N+1), D] bf16 (12.8 MB); tmp [196*CAP] (6.4 MB) ALIASES its head —
    // tmp is dead after bucketB, before fused<1> writes hidb. hidb's zero row
    // (offset 12.8 MB) is beyond tmp's extent, so init's write survives.
    ushort* hidb = (ushort*)ws;
    int* tmp     = (int*)ws;

    // ---- build padded CSR: count/cvt -> bin -> scans -> windowed scatter ----
    init_kernel<<<512, 256, 0, stream>>>(deg, cursor, xb, hidb);
    count_cvt_kernel<<<CNT_BLOCKS + CVT_BLOCKS, 512, 0, stream>>>(dst, deg, x, xb);
    bucketA_kernel<<<PA_BLOCKS, 512, 0, stream>>>(src, dst, cursor, tmp);
    degscan1_kernel<<<BUCKETS, 512, 0, stream>>>(deg, bsum);
    degscan2_kernel<<<BUCKETS, 512, 0, stream>>>(deg, bsum, offs);
    bucketB_kernel<<<BUCKETS, 512, 0, stream>>>(cursor, tmp, offs, srt);

    // ---- layer 1: hid = segsum(x) @ W1^T + b1 (bf16 gather; emits bf16 hid) ----
    fused_layer<1><<<NBLK, 256, 0, stream>>>(xb, offs, srt, W1, b1, hid, hidb);
    // ---- layer 2: out = segsum(hid) @ W1^T + b1 (bf16 gather) ----
    fused_layer<0><<<NBLK, 256, 0, stream>>>(hidb, offs, srt, W1, b1, out, (ushort*)nullptr);
}

// Round 9
// 209.080 us; speedup vs baseline: 1.5972x; 1.3043x over previous
//
#include <hip/hip_runtime.h>

#define N_NODES 100000
#define N_EDGES 1250000
#define D 64

#define BSHIFT 9
#define BUCKETS 196          // ceil(100000 / 512)
#define CAP 8192             // tmp capacity per bucket (mean 6378, +22 sigma)
#define CHUNK 4096           // edges per bucketA block
#define PA_BLOCKS ((N_EDGES + CHUNK - 1) / CHUNK)   // 306
#define CVT_BLOCKS 718       // merged-grid blocks doing fp32->bf16 convert
#define LCAP 64              // LDS list capacity per bucket per chunk (mean 21, max<64)
#define SRT_SLACK 256        // fused reads up to ~64 slots past a segment end
#define NBLK 2048

typedef long long ll;
typedef unsigned int uint;

// round-to-nearest-even fp32 -> bf16
__device__ __forceinline__ ushort f2bf(float f) {
    uint u = __float_as_uint(f);
    u += 0x7fffu + ((u >> 16) & 1u);
    return (ushort)(u >> 16);
}

// ---------- init: cursor[b]=b*CAP; offs[N] sentinel; zero rows (index N_NODES) ----------
__global__ void init_kernel(int* __restrict__ cursor, int* __restrict__ offs,
                            ushort* __restrict__ xb, ushort* __restrict__ hidb) {
    int t = threadIdx.x;
    if (t < BUCKETS) cursor[t] = t * CAP;
    if (t == 0) offs[N_NODES] = N_EDGES;
    if (t < 16) {   // zero row (index N_NODES) in both bf16 operands: 128 B each
        uint2 z; z.x = 0; z.y = 0;
        ((uint2*)(xb   + (ll)N_NODES * D))[t] = z;
        ((uint2*)(hidb + (ll)N_NODES * D))[t] = z;
    }
}

// ---------- pass A + cvt in one grid (R6-proven) ----------
// Blocks 0..PA_BLOCKS-1: bin edges into 196 coarse buckets (two-phase parallel
// flush). Blocks PA_BLOCKS..: fp32->bf16 convert of x, overlapped.
__global__ __launch_bounds__(512) void bucketA_cvt_kernel(const int* __restrict__ src,
                                                          const int* __restrict__ dst,
                                                          int* __restrict__ cursor,
                                                          int* __restrict__ tmp,
                                                          const float* __restrict__ x,
                                                          ushort* __restrict__ xb) {
    int tid = threadIdx.x;
    if (blockIdx.x >= PA_BLOCKS) {
        const int n4 = N_NODES * D / 4;
        int i = (blockIdx.x - PA_BLOCKS) * 512 + tid;
        const int stride = CVT_BLOCKS * 512;
        for (; i < n4; i += stride) {
            float4 v = ((const float4*)x)[i];
            ushort4 o;
            o.x = f2bf(v.x); o.y = f2bf(v.y); o.z = f2bf(v.z); o.w = f2bf(v.w);
            ((ushort4*)xb)[i] = o;
        }
        return;
    }

    __shared__ int lcnt[BUCKETS];
    __shared__ int gbs[BUCKETS];
    __shared__ int list[BUCKETS * LCAP];   // ~49 KB
    if (tid < BUCKETS) lcnt[tid] = 0;
    __syncthreads();

    int base = blockIdx.x * CHUNK;
    int nE = min(CHUNK, N_EDGES - base);
    for (int i = tid; i < nE; i += 512) {
        int e = base + i;
        int s = src[e], d = dst[e];
        int b = d >> BSHIFT;
        int p = atomicAdd(&lcnt[b], 1);            // LDS atomic, cheap
        list[b * LCAP + p] = s | ((d & 511) << 17); // src:17b, dstLow:9b
    }
    __syncthreads();

    if (tid < BUCKETS) gbs[tid] = atomicAdd(&cursor[tid], lcnt[tid]);  // parallel
    __syncthreads();

    int wv = tid >> 6, lane = tid & 63;
    for (int b = wv; b < BUCKETS; b += 8) {        // 8 waves, fire-and-forget stores
        int c = lcnt[b];
        if (lane < c) tmp[gbs[b] + lane] = list[b * LCAP + lane];
    }
}

// ---------- pass B: per-bucket local sort -> final srt + offs (R6-proven) ----------
// Wave-shuffle scans (4 barriers). Unpadded, contiguous CSR.
__global__ __launch_bounds__(512) void bucketB_kernel(const int* __restrict__ cursor,
                                                      const int* __restrict__ tmp,
                                                      int* __restrict__ srt,
                                                      int* __restrict__ offs) {
    __shared__ int hist[512];
    __shared__ int cur[512];
    __shared__ int sbase[256];
    __shared__ int wsum[8];
    const int b = blockIdx.x, tid = threadIdx.x;
    const int wv = tid >> 6, lane = tid & 63;
    const int cbase = b * CAP;
    const int cnt = cursor[b] - cbase;

    hist[tid] = 0;
    // wave 0: exclusive scan over the 196 bucket counts (4 buckets/lane + shfl)
    if (wv == 0) {
        int c0, c1, c2, c3;
        const int b4 = lane << 2;
        c0 = (b4     < BUCKETS) ? (cursor[b4]     - (b4    ) * CAP) : 0;
        c1 = (b4 + 1 < BUCKETS) ? (cursor[b4 + 1] - (b4 + 1) * CAP) : 0;
        c2 = (b4 + 2 < BUCKETS) ? (cursor[b4 + 2] - (b4 + 2) * CAP) : 0;
        c3 = (b4 + 3 < BUCKETS) ? (cursor[b4 + 3] - (b4 + 3) * CAP) : 0;
        const int s1 = c0 + c1, sum = s1 + c2 + c3;
        int run = sum;
#pragma unroll
        for (int d = 1; d < 64; d <<= 1) {
            int t = __shfl_up(run, d);
            if (lane >= d) run += t;
        }
        const int lex = run - sum;        // exclusive prefix of this lane's group
        sbase[b4]     = lex;
        sbase[b4 + 1] = lex + c0;
        sbase[b4 + 2] = lex + s1;
        sbase[b4 + 3] = lex + s1 + c2;
    }
    __syncthreads();
    const int gbase = sbase[b];

    for (int i = tid; i < cnt; i += 512) {
        int ln = tmp[cbase + i] >> 17;
        atomicAdd(&hist[ln], 1);          // LDS atomic, avg 12.5/node
    }
    __syncthreads();

    // 512-wide exclusive scan: per-wave shfl inclusive scan + wave-offset add
    const int x = hist[tid];
    int v = x;
#pragma unroll
    for (int d = 1; d < 64; d <<= 1) {
        int t = __shfl_up(v, d);
        if (lane >= d) v += t;
    }
    if (lane == 63) wsum[wv] = v;
    __syncthreads();
    int woff = 0;
#pragma unroll
    for (int k = 0; k < 8; ++k) woff += (k < wv) ? wsum[k] : 0;   // LDS broadcasts
    const int excl = v + woff - x;
    cur[tid] = excl;

    const int node0 = b << BSHIFT;
    const int nloc = min(512, N_NODES - node0);
    if (tid < nloc) offs[node0 + tid] = gbase + excl;   // coalesced
    __syncthreads();

    for (int i = tid; i < cnt; i += 512) {
        int t = tmp[cbase + i];            // L2-hot (second read)
        int ln = t >> 17;
        int p = atomicAdd(&cur[ln], 1);
        srt[gbase + p] = t & 0x1FFFF;      // random within 25KB window, L2-buffered
    }
}

// ---------- fused pull + linear: bf16 gather, node-pair, read-time sentinel ----------
// R8's winning body (VGPR=64, occ 34%, 59us) on the UNPADDED CSR: per
// iteration one coalesced 16-slot srt load per node (srt has tail slack, no
// address clamp), then per-slot cndmask to the zero-row sentinel (index
// N_NODES) for slots past the segment end. shfl distributes the 16 indices to
// the 4 gather groups; 4 uint2 gathers per node -> 10 VMEM/iter, 8 row-gathers
// in flight. NO min-waves launch bound (R4: forcing -> spills).
#define UACC(V, AX, AY, AZ, AW)                               \
    AX += __uint_as_float((V).x << 16);                       \
    AY += __uint_as_float((V).x & 0xffff0000u);               \
    AZ += __uint_as_float((V).y << 16);                       \
    AW += __uint_as_float((V).y & 0xffff0000u);

template<int EMIT>
__global__ __launch_bounds__(256) void fused_layer(const ushort* __restrict__ hb,
                                                   const int* __restrict__ offs,
                                                   const int* __restrict__ srt,
                                                   const float* __restrict__ W1,
                                                   const float* __restrict__ b1,
                                                   float* __restrict__ out,
                                                   ushort* __restrict__ outb) {
    __shared__ __align__(16) float rbA[4][64];
    __shared__ __align__(16) float rbB[4][64];
    const int tid  = threadIdx.x;
    const int lane = tid & 63;
    const int wid  = tid >> 6;
    const int g    = lane >> 4;          // gather group 0..3
    const int sub  = lane & 15;          // uint2 (4 bf16) within row; also srt slot
    const uint roff = (uint)sub << 3;    // byte offset within 128-B row
    const int goff = g << 2;
    const int gw   = blockIdx.x * 4 + wid;
    const int GW   = NBLK * 4;
    const char* hbase = (const char*)hb;

    const float4* wrow = (const float4*)(W1 + lane * D);
    const float bj = b1[lane];

    for (int p = gw; p < (N_NODES >> 1); p += GW) {
        const int nA = p << 1;
        const int2 o2 = *(const int2*)(offs + nA);   // begA, endA(=begB)
        const int begA = o2.x;
        const int endA = o2.y;
        const int endB = offs[nA + 2];               // offs[N] sentinel

        float aAx = 0.f, aAy = 0.f, aAz = 0.f, aAw = 0.f;
        float aBx = 0.f, aBy = 0.f, aBz = 0.f, aBw = 0.f;

        int ebA = begA, ebB = endA;
        while (ebA < endA || ebB < endB) {
            // one coalesced 16-slot srt load per node (slack past N_EDGES);
            // per-slot sentinel for slots beyond the segment end
            int siA = srt[ebA + sub];
            int siB = srt[ebB + sub];
            siA = (ebA + sub < endA) ? siA : N_NODES;
            siB = (ebB + sub < endB) ? siB : N_NODES;
            const int iA0 = __shfl(siA, goff);
            const int iA1 = __shfl(siA, goff + 1);
            const int iA2 = __shfl(siA, goff + 2);
            const int iA3 = __shfl(siA, goff + 3);
            const int iB0 = __shfl(siB, goff);
            const int iB1 = __shfl(siB, goff + 1);
            const int iB2 = __shfl(siB, goff + 2);
            const int iB3 = __shfl(siB, goff + 3);
            const uint2 vA0 = *(const uint2*)(hbase + (((uint)iA0 << 7) + roff));
            const uint2 vA1 = *(const uint2*)(hbase + (((uint)iA1 << 7) + roff));
            const uint2 vA2 = *(const uint2*)(hbase + (((uint)iA2 << 7) + roff));
            const uint2 vA3 = *(const uint2*)(hbase + (((uint)iA3 << 7) + roff));
            const uint2 vB0 = *(const uint2*)(hbase + (((uint)iB0 << 7) + roff));
            const uint2 vB1 = *(const uint2*)(hbase + (((uint)iB1 << 7) + roff));
            const uint2 vB2 = *(const uint2*)(hbase + (((uint)iB2 << 7) + roff));
            const uint2 vB3 = *(const uint2*)(hbase + (((uint)iB3 << 7) + roff));
            UACC(vA0, aAx, aAy, aAz, aAw);
            UACC(vA1, aAx, aAy, aAz, aAw);
            UACC(vA2, aAx, aAy, aAz, aAw);
            UACC(vA3, aAx, aAy, aAz, aAw);
            UACC(vB0, aBx, aBy, aBz, aBw);
            UACC(vB1, aBx, aBy, aBz, aBw);
            UACC(vB2, aBx, aBy, aBz, aBw);
            UACC(vB3, aBx, aBy, aBz, aBw);
            ebA += 16; ebB += 16;
        }

        // cross-group reduce: after xor16+xor32 every lane holds the full sum
        aAx += __shfl_xor(aAx, 16); aAy += __shfl_xor(aAy, 16);
        aAz += __shfl_xor(aAz, 16); aAw += __shfl_xor(aAw, 16);
        aBx += __shfl_xor(aBx, 16); aBy += __shfl_xor(aBy, 16);
        aBz += __shfl_xor(aBz, 16); aBw += __shfl_xor(aBw, 16);
        aAx += __shfl_xor(aAx, 32); aAy += __shfl_xor(aAy, 32);
        aAz += __shfl_xor(aAz, 32); aAw += __shfl_xor(aAw, 32);
        aBx += __shfl_xor(aBx, 32); aBy += __shfl_xor(aBy, 32);
        aBz += __shfl_xor(aBz, 32); aBw += __shfl_xor(aBw, 32);

        if (g == 0) {
            float4 t; t.x = aAx; t.y = aAy; t.z = aAz; t.w = aAw;
            *((float4*)rbA[wid] + sub) = t;     // lanes 0-15 consecutive: conflict-free
        }
        if (g == 1) {
            float4 t; t.x = aBx; t.y = aBy; t.z = aBz; t.w = aBw;
            *((float4*)rbB[wid] + sub) = t;
        }
        // wave-internal LDS RAW: compiler inserts lgkmcnt wait; no barrier needed

        float oA = bj, oB = bj;
        const float4* ra = (const float4*)rbA[wid];
        const float4* rb = (const float4*)rbB[wid];
#pragma unroll
        for (int k4 = 0; k4 < 16; ++k4) {
            const float4 w  = wrow[k4];          // L1-resident (16KB), per-lane row
            const float4 rA = ra[k4];            // LDS broadcast, conflict-free
            const float4 rB = rb[k4];
            oA += rA.x * w.x + rA.y * w.y + rA.z * w.z + rA.w * w.w;
            oB += rB.x * w.x + rB.y * w.y + rB.z * w.z + rB.w * w.w;
        }
        __builtin_nontemporal_store(oA, out + (ll)nA * D + lane);
        __builtin_nontemporal_store(oB, out + (ll)(nA + 1) * D + lane);
        if (EMIT) {
            outb[(ll)nA * D + lane]       = f2bf(oA);   // plain store: keep L2-hot
            outb[(ll)(nA + 1) * D + lane] = f2bf(oB);
        }
    }
}

extern "C" void kernel_launch(void* const* d_in, const int* in_sizes, int n_in,
                              void* d_out, int out_size, void* d_ws, size_t ws_size,
                              hipStream_t stream) {
    const float* x  = (const float*)d_in[0];   // [N, D]
    const int* edge = (const int*)d_in[1];     // [2, E]: src row then dst row
    const float* W1 = (const float*)d_in[2];   // [D, D]
    const float* b1 = (const float*)d_in[3];   // [D]

    const int* src = edge;
    const int* dst = edge + N_EDGES;

    float* out = (float*)d_out;                    // output 0: [N, D]
    float* hid = (float*)d_out + (ll)N_NODES * D;  // output 1: [N, D]

    // xb (bf16 copy of x, N+1 rows incl zero row) lives in the `out` region:
    // only read during layer 1 (which writes hid); layer 2 overwrites out fully.
    ushort* xb = (ushort*)d_out;                   // 12.81 MB < 25.6 MB

    // workspace layout (~24.7 MiB; 25.6 MB proven available)
    char* ws = (char*)d_ws;
    int* cursor = (int*)ws;  ws += 1024;                                          // [196]
    int* offs   = (int*)ws;  ws += ((size_t)(N_NODES + 1) * 4 + 255) & ~255ull;   // [N+1]
    int* srt    = (int*)ws;  ws += ((size_t)(N_EDGES + SRT_SLACK) * 4 + 255) & ~255ull;
    ushort* hidb = (ushort*)ws; ws += (size_t)(N_NODES + 1) * D * 2;              // [(N+1),D]
    int* tmp    = (int*)ws;                                                       // [196*CAP]

    // ---- build CSR (bucket sort) with cvt overlapped in the same grid ----
    init_kernel<<<1, 256, 0, stream>>>(cursor, offs, xb, hidb);
    bucketA_cvt_kernel<<<PA_BLOCKS + CVT_BLOCKS, 512, 0, stream>>>(src, dst, cursor,
                                                                   tmp, x, xb);
    bucketB_kernel<<<BUCKETS, 512, 0, stream>>>(cursor, tmp, srt, offs);

    // ---- layer 1: hid = segsum(x) @ W1^T + b1 (bf16 gather; emits bf16 hid) ----
    fused_layer<1><<<NBLK, 256, 0, stream>>>(xb, offs, srt, W1, b1, hid, hidb);
    // ---- layer 2: out = segsum(hid) @ W1^T + b1 (bf16 gather) ----
    fused_layer<0><<<NBLK, 256, 0, stream>>>(hidb, offs, srt, W1, b1, out, (ushort*)nullptr);
}

// Round 11
// 208.740 us; speedup vs baseline: 1.5998x; 1.0016x over previous
//
#include <hip/hip_runtime.h>

#define N_NODES 100000
#define N_EDGES 1250000
#define D 64

#define BSHIFT 9
#define BUCKETS 196          // ceil(100000 / 512)
#define CAP 8192             // tmp capacity per bucket (mean 6378, +22 sigma)
#define CHUNK 4096           // edges per bucketA block
#define PA_BLOCKS ((N_EDGES + CHUNK - 1) / CHUNK)   // 306
#define CVT_BLOCKS 718       // merged-grid blocks doing fp32->bf16 convert
#define LCAP 64              // LDS list capacity per bucket per chunk (mean 21, max<64)
#define SRT_SLACK 256        // fused reads up to ~64 slots past a segment end
#define NBLK 2048

typedef long long ll;
typedef unsigned int uint;

// round-to-nearest-even fp32 -> bf16
__device__ __forceinline__ ushort f2bf(float f) {
    uint u = __float_as_uint(f);
    u += 0x7fffu + ((u >> 16) & 1u);
    return (ushort)(u >> 16);
}

// ---------- init: cursor[b]=b*CAP; offs[N] sentinel; zero rows (index N_NODES) ----------
__global__ void init_kernel(int* __restrict__ cursor, int* __restrict__ offs,
                            ushort* __restrict__ xb, ushort* __restrict__ hidb) {
    int t = threadIdx.x;
    if (t < BUCKETS) cursor[t] = t * CAP;
    if (t == 0) offs[N_NODES] = N_EDGES;
    if (t < 16) {   // zero row (index N_NODES) in both bf16 operands: 128 B each
        uint2 z; z.x = 0; z.y = 0;
        ((uint2*)(xb   + (ll)N_NODES * D))[t] = z;
        ((uint2*)(hidb + (ll)N_NODES * D))[t] = z;
    }
}

// ---------- pass A + cvt in one grid ----------
// Blocks 0..PA_BLOCKS-1: bin edges into 196 coarse buckets. Binning loop is
// int4-vectorized: each thread issues its 2 edge-quad loads up-front (latency
// paid once, not 8x), then runs the LDS atomic+store chain from registers.
// Blocks PA_BLOCKS..: fp32->bf16 convert of x, overlapped.
__global__ __launch_bounds__(512) void bucketA_cvt_kernel(const int* __restrict__ src,
                                                          const int* __restrict__ dst,
                                                          int* __restrict__ cursor,
                                                          int* __restrict__ tmp,
                                                          const float* __restrict__ x,
                                                          ushort* __restrict__ xb) {
    int tid = threadIdx.x;
    if (blockIdx.x >= PA_BLOCKS) {
        const int n4 = N_NODES * D / 4;
        int i = (blockIdx.x - PA_BLOCKS) * 512 + tid;
        const int stride = CVT_BLOCKS * 512;
        for (; i < n4; i += stride) {
            float4 v = ((const float4*)x)[i];
            ushort4 o;
            o.x = f2bf(v.x); o.y = f2bf(v.y); o.z = f2bf(v.z); o.w = f2bf(v.w);
            ((ushort4*)xb)[i] = o;
        }
        return;
    }

    __shared__ int lcnt[BUCKETS];
    __shared__ int gbs[BUCKETS];
    __shared__ int list[BUCKETS * LCAP];   // ~49 KB
    if (tid < BUCKETS) lcnt[tid] = 0;
    __syncthreads();

    const int base = blockIdx.x * CHUNK;
    const int nE4 = min(CHUNK, N_EDGES - base) >> 2;   // CHUNK, N_EDGES mult of 16
    const int b4  = base >> 2;
    for (int i = tid; i < nE4; i += 512) {
        const int4 s4 = ((const int4*)src)[b4 + i];
        const int4 d4 = ((const int4*)dst)[b4 + i];
        int b, p;
        b = d4.x >> BSHIFT; p = atomicAdd(&lcnt[b], 1);
        list[b * LCAP + p] = s4.x | ((d4.x & 511) << 17);
        b = d4.y >> BSHIFT; p = atomicAdd(&lcnt[b], 1);
        list[b * LCAP + p] = s4.y | ((d4.y & 511) << 17);
        b = d4.z >> BSHIFT; p = atomicAdd(&lcnt[b], 1);
        list[b * LCAP + p] = s4.z | ((d4.z & 511) << 17);
        b = d4.w >> BSHIFT; p = atomicAdd(&lcnt[b], 1);
        list[b * LCAP + p] = s4.w | ((d4.w & 511) << 17);
    }
    __syncthreads();

    if (tid < BUCKETS) gbs[tid] = atomicAdd(&cursor[tid], lcnt[tid]);  // parallel
    __syncthreads();

    int wv = tid >> 6, lane = tid & 63;
    for (int b = wv; b < BUCKETS; b += 8) {        // 8 waves, fire-and-forget stores
        int c = lcnt[b];
        if (lane < c) tmp[gbs[b] + lane] = list[b * LCAP + lane];
    }
}

// ---------- pass B: per-bucket local sort -> final srt + offs ----------
// tmp is staged into LDS ONCE (hist fused into the load loop); the scatter
// pass reads LDS, not global. Wave-shuffle scans (4 barriers).
__global__ __launch_bounds__(512) void bucketB_kernel(const int* __restrict__ cursor,
                                                      const int* __restrict__ tmp,
                                                      int* __restrict__ srt,
                                                      int* __restrict__ offs) {
    __shared__ int list[CAP];          // 32 KB: the bucket's full payload
    __shared__ int hist[512];
    __shared__ int cur[512];
    __shared__ int sbase[256];
    __shared__ int wsum[8];
    const int b = blockIdx.x, tid = threadIdx.x;
    const int wv = tid >> 6, lane = tid & 63;
    const int cbase = b * CAP;
    const int cnt = cursor[b] - cbase;

    hist[tid] = 0;
    // wave 0: exclusive scan over the 196 bucket counts (4 buckets/lane + shfl)
    if (wv == 0) {
        int c0, c1, c2, c3;
        const int q4 = lane << 2;
        c0 = (q4     < BUCKETS) ? (cursor[q4]     - (q4    ) * CAP) : 0;
        c1 = (q4 + 1 < BUCKETS) ? (cursor[q4 + 1] - (q4 + 1) * CAP) : 0;
        c2 = (q4 + 2 < BUCKETS) ? (cursor[q4 + 2] - (q4 + 2) * CAP) : 0;
        c3 = (q4 + 3 < BUCKETS) ? (cursor[q4 + 3] - (q4 + 3) * CAP) : 0;
        const int s1 = c0 + c1, sum = s1 + c2 + c3;
        int run = sum;
#pragma unroll
        for (int d = 1; d < 64; d <<= 1) {
            int t = __shfl_up(run, d);
            if (lane >= d) run += t;
        }
        const int lex = run - sum;        // exclusive prefix of this lane's group
        sbase[q4]     = lex;
        sbase[q4 + 1] = lex + c0;
        sbase[q4 + 2] = lex + s1;
        sbase[q4 + 3] = lex + s1 + c2;
    }
    __syncthreads();                      // hist zeroed + sbase ready
    const int gbase = sbase[b];

    // stage tmp -> LDS once; hist on the fly
    for (int i = tid; i < cnt; i += 512) {
        int v = tmp[cbase + i];
        list[i] = v;
        atomicAdd(&hist[v >> 17], 1);     // LDS atomic, avg 12.5/node
    }
    __syncthreads();

    // 512-wide exclusive scan: per-wave shfl inclusive scan + wave-offset add
    const int x = hist[tid];
    int v = x;
#pragma unroll
    for (int d = 1; d < 64; d <<= 1) {
        int t = __shfl_up(v, d);
        if (lane >= d) v += t;
    }
    if (lane == 63) wsum[wv] = v;
    __syncthreads();
    int woff = 0;
#pragma unroll
    for (int k = 0; k < 8; ++k) woff += (k < wv) ? wsum[k] : 0;   // LDS broadcasts
    const int excl = v + woff - x;
    cur[tid] = excl;

    const int node0 = b << BSHIFT;
    const int nloc = min(512, N_NODES - node0);
    if (tid < nloc) offs[node0 + tid] = gbase + excl;   // coalesced
    __syncthreads();

    // scatter from LDS (no global re-read); stores hit the bucket's ~25KB window
    for (int i = tid; i < cnt; i += 512) {
        int t = list[i];
        int ln = t >> 17;
        int p = atomicAdd(&cur[ln], 1);
        srt[gbase + p] = t & 0x1FFFF;
    }
}

// ---------- fused pull + linear: bf16 gather, node-pair, read-time sentinel ----------
// UNCHANGED from R9 (measured: VGPR=64, occ 34.8%, 57.3us/layer). Any added
// live value tips the 64-VGPR cliff and halves occupancy — do not touch.
#define UACC(V, AX, AY, AZ, AW)                               \
    AX += __uint_as_float((V).x << 16);                       \
    AY += __uint_as_float((V).x & 0xffff0000u);               \
    AZ += __uint_as_float((V).y << 16);                       \
    AW += __uint_as_float((V).y & 0xffff0000u);

template<int EMIT>
__global__ __launch_bounds__(256) void fused_layer(const ushort* __restrict__ hb,
                                                   const int* __restrict__ offs,
                                                   const int* __restrict__ srt,
                                                   const float* __restrict__ W1,
                                                   const float* __restrict__ b1,
                                                   float* __restrict__ out,
                                                   ushort* __restrict__ outb) {
    __shared__ __align__(16) float rbA[4][64];
    __shared__ __align__(16) float rbB[4][64];
    const int tid  = threadIdx.x;
    const int lane = tid & 63;
    const int wid  = tid >> 6;
    const int g    = lane >> 4;          // gather group 0..3
    const int sub  = lane & 15;          // uint2 (4 bf16) within row; also srt slot
    const uint roff = (uint)sub << 3;    // byte offset within 128-B row
    const int goff = g << 2;
    const int gw   = blockIdx.x * 4 + wid;
    const int GW   = NBLK * 4;
    const char* hbase = (const char*)hb;

    const float4* wrow = (const float4*)(W1 + lane * D);
    const float bj = b1[lane];

    for (int p = gw; p < (N_NODES >> 1); p += GW) {
        const int nA = p << 1;
        const int2 o2 = *(const int2*)(offs + nA);   // begA, endA(=begB)
        const int begA = o2.x;
        const int endA = o2.y;
        const int endB = offs[nA + 2];               // offs[N] sentinel

        float aAx = 0.f, aAy = 0.f, aAz = 0.f, aAw = 0.f;
        float aBx = 0.f, aBy = 0.f, aBz = 0.f, aBw = 0.f;

        int ebA = begA, ebB = endA;
        while (ebA < endA || ebB < endB) {
            // one coalesced 16-slot srt load per node (slack past N_EDGES);
            // per-slot sentinel for slots beyond the segment end
            int siA = srt[ebA + sub];
            int siB = srt[ebB + sub];
            siA = (ebA + sub < endA) ? siA : N_NODES;
            siB = (ebB + sub < endB) ? siB : N_NODES;
            const int iA0 = __shfl(siA, goff);
            const int iA1 = __shfl(siA, goff + 1);
            const int iA2 = __shfl(siA, goff + 2);
            const int iA3 = __shfl(siA, goff + 3);
            const int iB0 = __shfl(siB, goff);
            const int iB1 = __shfl(siB, goff + 1);
            const int iB2 = __shfl(siB, goff + 2);
            const int iB3 = __shfl(siB, goff + 3);
            const uint2 vA0 = *(const uint2*)(hbase + (((uint)iA0 << 7) + roff));
            const uint2 vA1 = *(const uint2*)(hbase + (((uint)iA1 << 7) + roff));
            const uint2 vA2 = *(const uint2*)(hbase + (((uint)iA2 << 7) + roff));
            const uint2 vA3 = *(const uint2*)(hbase + (((uint)iA3 << 7) + roff));
            const uint2 vB0 = *(const uint2*)(hbase + (((uint)iB0 << 7) + roff));
            const uint2 vB1 = *(const uint2*)(hbase + (((uint)iB1 << 7) + roff));
            const uint2 vB2 = *(const uint2*)(hbase + (((uint)iB2 << 7) + roff));
            const uint2 vB3 = *(const uint2*)(hbase + (((uint)iB3 << 7) + roff));
            UACC(vA0, aAx, aAy, aAz, aAw);
            UACC(vA1, aAx, aAy, aAz, aAw);
            UACC(vA2, aAx, aAy, aAz, aAw);
            UACC(vA3, aAx, aAy, aAz, aAw);
            UACC(vB0, aBx, aBy, aBz, aBw);
            UACC(vB1, aBx, aBy, aBz, aBw);
            UACC(vB2, aBx, aBy, aBz, aBw);
            UACC(vB3, aBx, aBy, aBz, aBw);
            ebA += 16; ebB += 16;
        }

        // cross-group reduce: after xor16+xor32 every lane holds the full sum
        aAx += __shfl_xor(aAx, 16); aAy += __shfl_xor(aAy, 16);
        aAz += __shfl_xor(aAz, 16); aAw += __shfl_xor(aAw, 16);
        aBx += __shfl_xor(aBx, 16); aBy += __shfl_xor(aBy, 16);
        aBz += __shfl_xor(aBz, 16); aBw += __shfl_xor(aBw, 16);
        aAx += __shfl_xor(aAx, 32); aAy += __shfl_xor(aAy, 32);
        aAz += __shfl_xor(aAz, 32); aAw += __shfl_xor(aAw, 32);
        aBx += __shfl_xor(aBx, 32); aBy += __shfl_xor(aBy, 32);
        aBz += __shfl_xor(aBz, 32); aBw += __shfl_xor(aBw, 32);

        if (g == 0) {
            float4 t; t.x = aAx; t.y = aAy; t.z = aAz; t.w = aAw;
            *((float4*)rbA[wid] + sub) = t;     // lanes 0-15 consecutive: conflict-free
        }
        if (g == 1) {
            float4 t; t.x = aBx; t.y = aBy; t.z = aBz; t.w = aBw;
            *((float4*)rbB[wid] + sub) = t;
        }
        // wave-internal LDS RAW: compiler inserts lgkmcnt wait; no barrier needed

        float oA = bj, oB = bj;
        const float4* ra = (const float4*)rbA[wid];
        const float4* rb = (const float4*)rbB[wid];
#pragma unroll
        for (int k4 = 0; k4 < 16; ++k4) {
            const float4 w  = wrow[k4];          // L1-resident (16KB), per-lane row
            const float4 rA = ra[k4];            // LDS broadcast, conflict-free
            const float4 rB = rb[k4];
            oA += rA.x * w.x + rA.y * w.y + rA.z * w.z + rA.w * w.w;
            oB += rB.x * w.x + rB.y * w.y + rB.z * w.z + rB.w * w.w;
        }
        __builtin_nontemporal_store(oA, out + (ll)nA * D + lane);
        __builtin_nontemporal_store(oB, out + (ll)(nA + 1) * D + lane);
        if (EMIT) {
            outb[(ll)nA * D + lane]       = f2bf(oA);   // plain store: keep L2-hot
            outb[(ll)(nA + 1) * D + lane] = f2bf(oB);
        }
    }
}

extern "C" void kernel_launch(void* const* d_in, const int* in_sizes, int n_in,
                              void* d_out, int out_size, void* d_ws, size_t ws_size,
                              hipStream_t stream) {
    const float* x  = (const float*)d_in[0];   // [N, D]
    const int* edge = (const int*)d_in[1];     // [2, E]: src row then dst row
    const float* W1 = (const float*)d_in[2];   // [D, D]
    const float* b1 = (const float*)d_in[3];   // [D]

    const int* src = edge;
    const int* dst = edge + N_EDGES;

    float* out = (float*)d_out;                    // output 0: [N, D]
    float* hid = (float*)d_out + (ll)N_NODES * D;  // output 1: [N, D]

    // xb (bf16 copy of x, N+1 rows incl zero row) lives in the `out` region:
    // only read during layer 1 (which writes hid); layer 2 overwrites out fully.
    ushort* xb = (ushort*)d_out;                   // 12.81 MB < 25.6 MB

    // workspace layout (~24.7 MiB; 25.6 MB proven available)
    char* ws = (char*)d_ws;
    int* cursor = (int*)ws;  ws += 1024;                                          // [196]
    int* offs   = (int*)ws;  ws += ((size_t)(N_NODES + 1) * 4 + 255) & ~255ull;   // [N+1]
    int* srt    = (int*)ws;  ws += ((size_t)(N_EDGES + SRT_SLACK) * 4 + 255) & ~255ull;
    ushort* hidb = (ushort*)ws; ws += (size_t)(N_NODES + 1) * D * 2;              // [(N+1),D]
    int* tmp    = (int*)ws;                                                       // [196*CAP]

    // ---- build CSR (bucket sort) with cvt overlapped in the same grid ----
    init_kernel<<<1, 256, 0, stream>>>(cursor, offs, xb, hidb);
    bucketA_cvt_kernel<<<PA_BLOCKS + CVT_BLOCKS, 512, 0, stream>>>(src, dst, cursor,
                                                                   tmp, x, xb);
    bucketB_kernel<<<BUCKETS, 512, 0, stream>>>(cursor, tmp, srt, offs);

    // ---- layer 1: hid = segsum(x) @ W1^T + b1 (bf16 gather; emits bf16 hid) ----
    fused_layer<1><<<NBLK, 256, 0, stream>>>(xb, offs, srt, W1, b1, hid, hidb);
    // ---- layer 2: out = segsum(hid) @ W1^T + b1 (bf16 gather) ----
    fused_layer<0><<<NBLK, 256, 0, stream>>>(hidb, offs, srt, W1, b1, out, (ushort*)nullptr);
}